// Round 7
// baseline (230.201 us; speedup 1.0000x reference)
//
#include <hip/hip_runtime.h>

#define N_NODESC 100000
#define N_EDGESC 1600000
#define HCC 128                      // HEADS*OUT_CH
#define E_TOTC (N_EDGESC + N_NODESC) // edges + self loops
#define SCAN_NB 391                  // ceil(N_NODES/256)
#define PROJ_NB 782                  // ceil(N_NODES/128)

__device__ __forceinline__ float lrelu(float v) { return fmaxf(v, 0.2f * v); }
__device__ __forceinline__ unsigned short f2bf(float f) {   // RNE bf16
    unsigned u = __float_as_uint(f);
    unsigned r = ((u >> 16) & 1u) + 0x7fffu;
    return (unsigned short)((u + r) >> 16);
}

// ---- prep: WT[64][128] transpose + U[64][16] = [W_h^T att_src | W_h^T att_dst] ----
__global__ void wu_kernel(const float* __restrict__ W,
                          const float* __restrict__ att_src, const float* __restrict__ att_dst,
                          float* __restrict__ WT, float* __restrict__ us_g) {
    int t = blockIdx.x * 256 + threadIdx.x;
    if (t < 8192) {                       // transpose: WT[k][c] = W[c][k]
        int k = t >> 7, c = t & 127;
        WT[t] = W[c * 64 + k];
    } else {                              // U: us_g[k*16+c]
        int o = t - 8192;                 // 0..1023
        int k = o >> 4, c = o & 15;
        const int h = (c < 8) ? c : c - 8;
        const float* av = (c < 8) ? att_src : att_dst;
        float s = 0.f;
#pragma unroll
        for (int j = 0; j < 16; ++j) s += av[h * 16 + j] * W[(h * 16 + j) * 64 + k];
        us_g[o] = s;
    }
}

// ---- augmented projection GEMM: [N x 64] @ [64 x (128 h-cols + 16 a-cols)] ----
// 256 threads, 128 rows/block, 8x8 thread tile for h; each thread also does
// 8 rows x 1 a-col (col = t>>4) reusing the same xs tile. No shuffles anywhere.
__launch_bounds__(256, 2)
__global__ void proj_kernel(const float* __restrict__ x, const float* __restrict__ WT,
                            const float* __restrict__ us_g,
                            unsigned short* __restrict__ h16,
                            float* __restrict__ a_src, float* __restrict__ a_dst) {
    __shared__ float xs[128][68];
    __shared__ float ws[64][132];
    __shared__ float us[64][16];
    const int t = threadIdx.x;
    const int row0 = blockIdx.x * 128;

    const float4* wt4 = (const float4*)WT;
    float4* ws4 = (float4*)&ws[0][0];
#pragma unroll
    for (int j = 0; j < 8; ++j) {
        int q = t + 256 * j;               // float4 idx into WT [64][128]
        int k = q >> 5, c4 = q & 31;       // 32 float4 per row
        *(float4*)&ws[k][c4 * 4] = wt4[q];
    }
    ((float4*)&us[0][0])[t] = ((const float4*)us_g)[t];

#pragma unroll
    for (int j = 0; j < 8; ++j) {
        int f = (t + 256 * j) * 4;
        int r = f >> 6, k = f & 63;
        int gr = row0 + r;
        if (gr >= N_NODESC) gr = N_NODESC - 1;
        float4 v = *(const float4*)&x[(size_t)gr * 64 + k];
        *(float4*)&xs[r][k] = v;
    }
    __syncthreads();

    const int rg = t & 15;
    const int cg = t >> 4;
    float acc[8][8], acca[8];
#pragma unroll
    for (int i = 0; i < 8; ++i) {
        acca[i] = 0.f;
#pragma unroll
        for (int j = 0; j < 8; ++j) acc[i][j] = 0.f;
    }

#pragma unroll 4
    for (int k = 0; k < 64; ++k) {
        float xv[8];
#pragma unroll
        for (int i = 0; i < 8; ++i) xv[i] = xs[rg + 16 * i][k];
        float4 w0 = *(const float4*)&ws[k][4 * cg];
        float4 w1 = *(const float4*)&ws[k][64 + 4 * cg];
        float uv = us[k][cg];
#pragma unroll
        for (int i = 0; i < 8; ++i) {
            acc[i][0] += xv[i] * w0.x; acc[i][1] += xv[i] * w0.y;
            acc[i][2] += xv[i] * w0.z; acc[i][3] += xv[i] * w0.w;
            acc[i][4] += xv[i] * w1.x; acc[i][5] += xv[i] * w1.y;
            acc[i][6] += xv[i] * w1.z; acc[i][7] += xv[i] * w1.w;
            acca[i]   += xv[i] * uv;
        }
    }

#pragma unroll
    for (int i = 0; i < 8; ++i) {
        int gr = row0 + rg + 16 * i;
        if (gr < N_NODESC) {
            ushort4 p0, p1;
            p0.x = f2bf(acc[i][0]); p0.y = f2bf(acc[i][1]); p0.z = f2bf(acc[i][2]); p0.w = f2bf(acc[i][3]);
            p1.x = f2bf(acc[i][4]); p1.y = f2bf(acc[i][5]); p1.z = f2bf(acc[i][6]); p1.w = f2bf(acc[i][7]);
            *(ushort4*)&h16[(size_t)gr * HCC + 4 * cg] = p0;
            *(ushort4*)&h16[(size_t)gr * HCC + 64 + 4 * cg] = p1;
            if (cg < 8) a_src[(size_t)gr * 8 + cg] = acca[i];
            else        a_dst[(size_t)gr * 8 + cg - 8] = acca[i];
        }
    }
}

// ---- CSR pos pass: deg histogram + intra-segment position (standalone) ----
__global__ void pos_kernel(const int* __restrict__ ei, int* __restrict__ deg,
                           int* __restrict__ posb) {
    int e = blockIdx.x * 256 + threadIdx.x;
    if (e >= E_TOTC) return;
    int d = (e < N_EDGESC) ? ei[N_EDGESC + e] : (e - N_EDGESC);
    posb[e] = atomicAdd(&deg[d], 1);
}

__global__ void scan1_kernel(const int* __restrict__ deg, int* __restrict__ bsum) {
    __shared__ int lds[256];
    int i = blockIdx.x * 256 + threadIdx.x;
    lds[threadIdx.x] = (i < N_NODESC) ? deg[i] : 0;
    __syncthreads();
    for (int off = 128; off > 0; off >>= 1) {
        if (threadIdx.x < off) lds[threadIdx.x] += lds[threadIdx.x + off];
        __syncthreads();
    }
    if (threadIdx.x == 0) bsum[blockIdx.x] = lds[0];
}

__global__ void scan2_kernel(int* __restrict__ bsum) {
    __shared__ int lds[512];
    int t = threadIdx.x;
    lds[t] = (t < SCAN_NB) ? bsum[t] : 0;
    __syncthreads();
    for (int off = 1; off < 512; off <<= 1) {
        int u = 0;
        if (t >= off) u = lds[t - off];
        __syncthreads();
        if (t >= off) lds[t] += u;
        __syncthreads();
    }
    if (t < SCAN_NB) bsum[t] = (t == 0) ? 0 : lds[t - 1];
}

__global__ void scan3_kernel(const int* __restrict__ deg, const int* __restrict__ bsum,
                             int* __restrict__ rowptr) {
    __shared__ int lds[256];
    int t = threadIdx.x;
    int i = blockIdx.x * 256 + t;
    int v = (i < N_NODESC) ? deg[i] : 0;
    lds[t] = v;
    __syncthreads();
    for (int off = 1; off < 256; off <<= 1) {
        int u = 0;
        if (t >= off) u = lds[t - off];
        __syncthreads();
        if (t >= off) lds[t] += u;
        __syncthreads();
    }
    int excl = bsum[blockIdx.x] + lds[t] - v;
    if (i < N_NODESC) rowptr[i] = excl;
    if (i == 0) rowptr[N_NODESC] = E_TOTC;
}

__global__ void scatter_kernel(const int* __restrict__ ei, const int* __restrict__ rowptr,
                               const int* __restrict__ posb, int* __restrict__ colsrc) {
    int e = blockIdx.x * 256 + threadIdx.x;
    if (e >= E_TOTC) return;
    int s, d;
    if (e < N_EDGESC) { s = ei[e]; d = ei[N_EDGESC + e]; }
    else              { s = d = e - N_EDGESC; }
    colsrc[rowptr[d] + posb[e]] = s;
}

// ---- gather aggregation, no online max (softmax shift-invariant, logits small) ----
__launch_bounds__(256, 8)
__global__ void agg_csr_kernel(const int* __restrict__ rowptr, const int* __restrict__ colsrc,
                               const float* __restrict__ a_src, const float* __restrict__ a_dst,
                               const unsigned* __restrict__ h32,
                               const float* __restrict__ bias, float* __restrict__ out) {
    const int t = threadIdx.x;
    const int L = t & 63;
    const int n = blockIdx.x * 4 + (t >> 6);
    const int hd = L >> 3;
    const int eL = L & 7;

    const int beg = rowptr[n], end = rowptr[n + 1];
    const float ad = a_dst[n * 8 + hd];

    float den = 0.f;
    float acc[16];
#pragma unroll
    for (int j = 0; j < 16; ++j) acc[j] = 0.f;

    int p = beg + eL;
    bool vld = p < end;
    int s = vld ? colsrc[p] : 0;
    float av = vld ? a_src[s * 8 + hd] : 0.f;

    while (vld) {
        const uint4* hp = (const uint4*)(h32 + (size_t)s * 64 + hd * 8);
        const uint4 ha = hp[0];
        const uint4 hb = hp[1];
        const int p2 = p + 8;
        const bool v2 = p2 < end;
        const int s2 = v2 ? colsrc[p2] : 0;
        const float av2 = v2 ? a_src[s2 * 8 + hd] : 0.f;

        const float pr = __expf(lrelu(av + ad));
        den += pr;
        acc[0]  = fmaf(pr, __uint_as_float(ha.x << 16),         acc[0]);
        acc[1]  = fmaf(pr, __uint_as_float(ha.x & 0xffff0000u), acc[1]);
        acc[2]  = fmaf(pr, __uint_as_float(ha.y << 16),         acc[2]);
        acc[3]  = fmaf(pr, __uint_as_float(ha.y & 0xffff0000u), acc[3]);
        acc[4]  = fmaf(pr, __uint_as_float(ha.z << 16),         acc[4]);
        acc[5]  = fmaf(pr, __uint_as_float(ha.z & 0xffff0000u), acc[5]);
        acc[6]  = fmaf(pr, __uint_as_float(ha.w << 16),         acc[6]);
        acc[7]  = fmaf(pr, __uint_as_float(ha.w & 0xffff0000u), acc[7]);
        acc[8]  = fmaf(pr, __uint_as_float(hb.x << 16),         acc[8]);
        acc[9]  = fmaf(pr, __uint_as_float(hb.x & 0xffff0000u), acc[9]);
        acc[10] = fmaf(pr, __uint_as_float(hb.y << 16),         acc[10]);
        acc[11] = fmaf(pr, __uint_as_float(hb.y & 0xffff0000u), acc[11]);
        acc[12] = fmaf(pr, __uint_as_float(hb.z << 16),         acc[12]);
        acc[13] = fmaf(pr, __uint_as_float(hb.z & 0xffff0000u), acc[13]);
        acc[14] = fmaf(pr, __uint_as_float(hb.w << 16),         acc[14]);
        acc[15] = fmaf(pr, __uint_as_float(hb.w & 0xffff0000u), acc[15]);

        p = p2; s = s2; av = av2; vld = v2;
    }

    den += __shfl_xor(den, 1); den += __shfl_xor(den, 2); den += __shfl_xor(den, 4);
#pragma unroll
    for (int j = 0; j < 16; ++j) {
        acc[j] += __shfl_xor(acc[j], 1);
        acc[j] += __shfl_xor(acc[j], 2);
        acc[j] += __shfl_xor(acc[j], 4);
    }
    const float inv = 1.f / (den + 1e-16f);
    float ox = acc[0], oy = acc[1];
#pragma unroll
    for (int j = 1; j < 8; ++j) {
        ox = (eL == j) ? acc[2 * j]     : ox;
        oy = (eL == j) ? acc[2 * j + 1] : oy;
    }
    const float2 b = ((const float2*)bias)[L];
    float2 o;
    o.x = fmaxf(ox * inv + b.x, 0.f);
    o.y = fmaxf(oy * inv + b.y, 0.f);
    ((float2*)out)[(size_t)n * 64 + L] = o;
}

extern "C" void kernel_launch(void* const* d_in, const int* in_sizes, int n_in,
                              void* d_out, int out_size, void* d_ws, size_t ws_size,
                              hipStream_t stream) {
    const float* x       = (const float*)d_in[0];
    const int*   ei      = (const int*)d_in[1];
    const float* W       = (const float*)d_in[2];
    const float* att_src = (const float*)d_in[3];
    const float* att_dst = (const float*)d_in[4];
    const float* bias    = (const float*)d_in[5];
    float* out = (float*)d_out;

    float* ws    = (float*)d_ws;
    unsigned short* h16 = (unsigned short*)ws;   // 12,800,000 ushorts (6.4M float slots)
    float* a_src = ws + 6400000;                 //    800,000
    float* a_dst = a_src + 800000;               //    800,000
    float* WT    = a_dst + 800000;               //      8,192
    float* us_g  = WT + 8192;                    //      1,024
    int* deg     = (int*)(us_g + 1024);          //    100,000
    int* rowptr  = deg + 100000;                 //    100,001
    int* bsum    = rowptr + 100001;              //        512
    int* posb    = bsum + 512;                   //  1,700,000
    int* colsrc  = posb + 1700000;               //  1,700,000

    hipMemsetAsync(deg, 0, 100000 * sizeof(int), stream);

    wu_kernel<<<36, 256, 0, stream>>>(W, att_src, att_dst, WT, us_g);
    proj_kernel<<<PROJ_NB, 256, 0, stream>>>(x, WT, us_g, h16, a_src, a_dst);
    pos_kernel<<<(E_TOTC + 255) / 256, 256, 0, stream>>>(ei, deg, posb);
    scan1_kernel<<<SCAN_NB, 256, 0, stream>>>(deg, bsum);
    scan2_kernel<<<1, 512, 0, stream>>>(bsum);
    scan3_kernel<<<SCAN_NB, 256, 0, stream>>>(deg, bsum, rowptr);
    scatter_kernel<<<(E_TOTC + 255) / 256, 256, 0, stream>>>(ei, rowptr, posb, colsrc);

    agg_csr_kernel<<<N_NODESC / 4, 256, 0, stream>>>(rowptr, colsrc, a_src, a_dst,
                                                     (const unsigned*)h16, bias, out);
}